// Round 5
// baseline (336.423 us; speedup 1.0000x reference)
//
#include <hip/hip_runtime.h>
#include <math.h>

#define N_NODES 100000
#define D_FEAT  256
#define TOP_K   50000
#define NBINS   65536
#define NCHUNK  64          // NBINS / 1024 chunks for the parallel scan
#define CUTPOS  (N_NODES - TOP_K)
#define ROWSTRIDE 260       // 256 + 4 pad: bank = (4g + l + 8i) % 32 -> 2-way = free
#define NBITW   3200        // member bitmask words (ceil(100000/32)=3125, padded)
#define QGRID   2048        // emit||edge fused kernel (8 blocks/CU co-resident)
#define EMIT_CHUNKS 6250    // 8 rows per chunk = 50,000 rows
#define EDGE_CHUNK_SHIFT 9  // 512 pairs per chunk

// Workspace layout (byte offsets, all 16B-aligned):
//         0 : s32      float[N_NODES]   (400,000)
//   400,000 : ss       float[N_NODES]   (400,000)  bucket-sorted scores
//   800,000 : si       int[N_NODES]     (400,000)  bucket-sorted node ids
// 1,200,000 : hist     int[NBINS]       (262,144)  } contiguous zero region
// 1,462,144 : bits     uint[NBITW]      ( 12,800)  } (275,008 B memset)
// 1,474,944 : queue    int[1]           (own cacheline, zeroed with region)
// 1,562,144 : offs     int[NBINS]       (262,144)  chunk-LOCAL exclusive offsets
// 1,824,288 : cursor   int[NBINS]       (262,144)
// 2,086,432 : chunkSum int[NCHUNK]      (256)

__device__ __forceinline__ int bucket_of(float s) {
    int b = (int)(s * 65536.0f);
    return min(max(b, 0), NBINS - 1);
}

// numpy SIMD float32 exp (FMA universal-intrinsics path) — bit-exact, verified R6.
__device__ __forceinline__ float np_expf(float x) {
    float q  = rintf(x * 1.44269504088896341f);
    float xr = fmaf(-q, 0.693359375f, x);
    xr       = fmaf(-q, -2.12194440e-4f, xr);
    float x2 = xr * xr;
    float p  = 1.9875691500E-4f;
    p = fmaf(p, xr, 1.3981999507E-3f);
    p = fmaf(p, xr, 8.3334519073E-3f);
    p = fmaf(p, xr, 4.1665795894E-2f);
    p = fmaf(p, xr, 1.6666665459E-1f);
    p = fmaf(p, xr, 5.0000001201E-1f);
    p = fmaf(p, x2, xr);
    p = p + 1.0f;
    return ldexpf(p, (int)q);
}

// OpenBLAS sgemv_t emulation, parallelized 8 lanes/node (bit-exact numerics):
// lane 8g+l runs chain l (k = i*8+l, i=0..31, serial fmaf) for node g of its wave;
// merge via shfl_xor 1,2,4 reproduces ((a0+a1)+(a2+a3))+((a4+a5)+(a6+a7)).
// Block = 256 thr = 4 waves = 32 nodes; rows staged to LDS coalesced.
// DO NOT TOUCH the numerics: bit-exact scores gate the top-k tie boundary.
__global__ void score_kernel(const float* __restrict__ h,
                             const float* __restrict__ W,
                             const float* __restrict__ bvec,
                             float* __restrict__ s32,
                             int* __restrict__ hist) {
    __shared__ float rows[32 * ROWSTRIDE];   // 33,280 B
    __shared__ float wl[256];
    int tid  = threadIdx.x;
    int wave = tid >> 6;
    int lane = tid & 63;
    int g    = lane >> 3;    // node within wave's 8
    int l    = lane & 7;     // chain id

    wl[tid] = W[tid];

    // stage this wave's 8 rows: one float4 per lane per row, coalesced 1KB
    int nodeBase = blockIdx.x * 32 + wave * 8;
#pragma unroll
    for (int r = 0; r < 8; ++r) {
        float4 v = ((const float4*)(h + (size_t)(nodeBase + r) * D_FEAT))[lane];
        *((float4*)&rows[(wave * 8 + r) * ROWSTRIDE + lane * 4]) = v;
    }
    __syncthreads();

    // W chain-slice into registers: wreg[i] = W[i*8 + l] (8-way LDS broadcast, free)
    float wreg[32];
#pragma unroll
    for (int i = 0; i < 32; ++i) wreg[i] = wl[i * 8 + l];

    // serial chain: acc = sum_{i} h[node][i*8+l] * W[i*8+l], strict fmaf order
    const float* myrow = &rows[(wave * 8 + g) * ROWSTRIDE];
    float acc = 0.0f;
#pragma unroll
    for (int i = 0; i < 32; ++i)
        acc = fmaf(myrow[i * 8 + l], wreg[i], acc);

    // vhaddps-style adjacent-pairwise merge tree (lane 8g+0 holds node g's z)
    float b01 = acc + __shfl_xor(acc, 1, 64);
    float b23 = b01 + __shfl_xor(b01, 2, 64);
    float z   = b23 + __shfl_xor(b23, 4, 64);

    z = z + bvec[0];
    float t = np_expf(-z);
    float s = 1.0f / (1.0f + t);       // IEEE f32 divide

    if (l == 0) {
        int node = nodeBase + g;
        s32[node] = s;
        atomicAdd(&hist[bucket_of(s)], 1);
    }
}

// Parallel chunk scan: 64 blocks x 256 threads, 4 consecutive bins per thread
// (int4 coalesced). Chunk-LOCAL exclusive offsets into offs+cursor, chunk total
// into chunkSum. Global base recomputed in-register by consumer blocks (free).
__global__ void scan_chunks_kernel(const int* __restrict__ hist,
                                   int* __restrict__ offs,
                                   int* __restrict__ cursor,
                                   int* __restrict__ chunkSum) {
    __shared__ int wsum[4];
    int tid  = threadIdx.x;
    int lane = tid & 63;
    int wid  = tid >> 6;
    int base = blockIdx.x * 1024 + tid * 4;

    int4 hv = *((const int4*)(hist + base));
    int e1 = hv.x;
    int e2 = hv.x + hv.y;
    int e3 = e2 + hv.z;
    int tot = e3 + hv.w;

    int incl = tot;
#pragma unroll
    for (int d = 1; d < 64; d <<= 1) {
        int t = __shfl_up(incl, d, 64);
        if (lane >= d) incl += t;
    }
    if (lane == 63) wsum[wid] = incl;
    __syncthreads();
    int wbase = 0;
#pragma unroll
    for (int w = 0; w < 3; ++w)
        if (w < wid) wbase += wsum[w];

    int excl = wbase + (incl - tot);
    int4 ov = make_int4(excl, excl + e1, excl + e2, excl + e3);
    *((int4*)(offs + base))   = ov;
    *((int4*)(cursor + base)) = ov;
    if (tid == 255) chunkSum[blockIdx.x] = excl + tot;
}

// wave-0: exclusive scan of the 64 chunk totals -> sbase (LDS)
__device__ __forceinline__ void build_base(const int* __restrict__ chunkSum,
                                           int* sbase, int tid) {
    if (tid < 64) {
        int v = chunkSum[tid];
        int inc = v;
#pragma unroll
        for (int d = 1; d < 64; d <<= 1) {
            int t = __shfl_up(inc, d, 64);
            if (tid >= d) inc += t;
        }
        sbase[tid] = inc - v;
    }
}

// Scatter + sure-member marking.
//  - Buckets whose global END <= CUTPOS are never read downstream: skip the
//    cursor atomic AND the ss/si writes entirely (~half the scatter work).
//  - Buckets whose global START >= CUTPOS are fully inside the top-k: mark
//    member bit now (removes the emit->edge ordering dependency).
__global__ void scatter_kernel(const float* __restrict__ s32,
                               int* __restrict__ cursor,
                               const int* __restrict__ offs,
                               const int* __restrict__ chunkSum,
                               unsigned int* __restrict__ bits,
                               float* __restrict__ ss,
                               int* __restrict__ si) {
    __shared__ int sbase[64];
    int tid = threadIdx.x;
    build_base(chunkSum, sbase, tid);
    __syncthreads();
    int i = blockIdx.x * 256 + tid;
    if (i >= N_NODES) return;
    float s = s32[i];
    int b = bucket_of(s);
    int bn = b + 1;
    int gend = (bn == NBINS) ? N_NODES : sbase[bn >> 10] + offs[bn];
    if (gend <= CUTPOS) return;               // fully below cut: never read
    int pos = atomicAdd(&cursor[b], 1);       // chunk-local position
    int gbase = sbase[b >> 10];
    ss[gbase + pos] = s;
    si[gbase + pos] = i;
    if (gbase + offs[b] >= CUTPOS)            // fully above cut: sure member
        atomicOr(&bits[(unsigned)i >> 5], 1u << (i & 31));
}

// One thread per bucket; insertion sort ascending by (s asc, idx desc)
// so reversed (descending) order is (s desc, idx asc) — lax.top_k tie rule.
// Buckets entirely below the cut are never read -> skip. The (single)
// boundary bucket marks its suffix's member bits after sorting.
__global__ void bucket_sort_kernel(const int* __restrict__ offs,
                                   const int* __restrict__ chunkSum,
                                   unsigned int* __restrict__ bits,
                                   float* __restrict__ ss,
                                   int* __restrict__ si) {
    __shared__ int sbase[64];
    int tid = threadIdx.x;
    build_base(chunkSum, sbase, tid);
    __syncthreads();
    int b = blockIdx.x * 256 + tid;
    int s0 = sbase[b >> 10] + offs[b];
    int e  = (b == NBINS - 1) ? N_NODES : sbase[(b + 1) >> 10] + offs[b + 1];
    if (e <= CUTPOS) return;
    for (int i = s0 + 1; i < e; ++i) {
        float ks = ss[i];
        int   ki = si[i];
        int j = i - 1;
        while (j >= s0) {
            float ps = ss[j];
            int   pi = si[j];
            bool gt = (ps > ks) || (ps == ks && pi < ki);
            if (!gt) break;
            ss[j + 1] = ps;
            si[j + 1] = pi;
            --j;
        }
        ss[j + 1] = ks;
        si[j + 1] = ki;
    }
    if (s0 < CUTPOS) {                        // boundary bucket: mark suffix
        for (int i = CUTPOS; i < e; ++i) {
            int id = si[i];
            atomicOr(&bits[(unsigned)id >> 5], 1u << (id & 31));
        }
    }
}

__device__ __forceinline__ unsigned mem_bit(const unsigned int* __restrict__ bits,
                                            int s) {
    return (bits[(unsigned)s >> 5] >> (s & 31)) & 1u;
}

// Fused emit||edge with a self-balancing chunk queue.
// Work items: EMIT_CHUNKS chunks of 8 output rows, plus edge chunks of 512
// pairs. Items are interleaved 2:1 (e,e,g triples) so both traffic types flow
// concurrently; one atomicAdd per chunk, prefetched one chunk ahead so the
// grab latency hides under ~10us of chunk work. Imbalance cost drops to
// O(one chunk) regardless of actual gather-vs-stream effective bandwidth.
__global__ void emit_edge_kernel(const float* __restrict__ h,
                                 const float* __restrict__ ss,
                                 const int* __restrict__ si,
                                 const int* __restrict__ ei,
                                 const unsigned int* __restrict__ bits,
                                 int* __restrict__ queue,
                                 float* __restrict__ out_newh,
                                 float* __restrict__ out_ids,
                                 float* __restrict__ out_mask,
                                 int E) {
    __shared__ int sflag;
    __shared__ int snext;
    int tid  = threadIdx.x;
    int lane = tid & 63;
    int wv   = tid >> 6;

    if (tid < 64) {                           // int64-vs-int32 storage detect
        int v = ei[2 * tid + 1];
        unsigned long long m = __ballot(v == 0);
        if (tid == 0) sflag = (m == ~0ULL) ? 1 : 0;
    }

    int npairs = (E + 1) / 2;
    int nEdgeChunks = (npairs + ((1 << EDGE_CHUNK_SHIFT) - 1)) >> EDGE_CHUNK_SHIFT;
    int total = EMIT_CHUNKS + nEdgeChunks;
    bool interleave = (nEdgeChunks * 2 == EMIT_CHUNKS);

    if (tid == 0) snext = atomicAdd(queue, 1);
    __syncthreads();
    int flag = sflag;
    int c = snext;

    while (c < total) {
        int grabbed = 0;
        if (tid == 0) grabbed = atomicAdd(queue, 1);   // prefetch next chunk id

        // map chunk id -> work item
        int eIdx = -1, gIdx = -1;
        if (interleave) {
            int t = c / 3, r = c - 3 * t;              // triples {e,e,g}
            if (r < 2) eIdx = 2 * t + r; else gIdx = t;
        } else {
            if (c < EMIT_CHUNKS) eIdx = c; else gIdx = c - EMIT_CHUNKS;
        }

        if (eIdx >= 0) {
            // 8 rows: wave wv does rows eIdx*8 + wv*2 + {0,1}
            int rowBase = eIdx * 8 + wv * 2;
#pragma unroll
            for (int r = 0; r < 2; ++r) {
                int row = rowBase + r;
                int p = N_NODES - 1 - row;
                int id  = si[p];              // wave-uniform -> broadcast
                float s = ss[p];
                if (lane == 0) out_ids[row] = (float)id;
                const float4* hv = (const float4*)(h + (size_t)id * D_FEAT);
                float4 v = hv[lane];
                ((float4*)(out_newh + (size_t)row * D_FEAT))[lane] =
                    make_float4(v.x * s, v.y * s, v.z * s, v.w * s);
            }
        } else {
            int base = gIdx << EDGE_CHUNK_SHIFT;
#pragma unroll
            for (int j = 0; j < 2; ++j) {
                int k = base + j * 256 + tid;
                if (k >= npairs) break;
                int i0 = 2 * k;
                int i1 = i0 + 1;
                if (i1 < E) {
                    int s0, d0, s1, d1;
                    if (flag) {            // int64 storage: value in even dword
                        int4 a  = ((const int4*)ei)[k];
                        int4 bq = ((const int4*)(ei + 2 * (size_t)E))[k];
                        s0 = a.x;  s1 = a.z;
                        d0 = bq.x; d1 = bq.z;
                    } else {               // int32 storage
                        int2 a  = ((const int2*)ei)[k];
                        int2 bq = ((const int2*)(ei + (size_t)E))[k];
                        s0 = a.x;  s1 = a.y;
                        d0 = bq.x; d1 = bq.y;
                    }
                    bool ok0 = ((unsigned)s0 < (unsigned)N_NODES) &&
                               ((unsigned)d0 < (unsigned)N_NODES) &&
                               mem_bit(bits, s0) && mem_bit(bits, d0);
                    bool ok1 = ((unsigned)s1 < (unsigned)N_NODES) &&
                               ((unsigned)d1 < (unsigned)N_NODES) &&
                               mem_bit(bits, s1) && mem_bit(bits, d1);
                    ((float2*)out_mask)[k] = make_float2(ok0 ? 1.0f : 0.0f,
                                                         ok1 ? 1.0f : 0.0f);
                } else {                   // odd-E tail (not hit for E=3.2M)
                    int s0, d0;
                    if (flag) { s0 = ei[2 * i0]; d0 = ei[2 * ((size_t)E + i0)]; }
                    else      { s0 = ei[i0];     d0 = ei[(size_t)E + i0]; }
                    bool ok0 = ((unsigned)s0 < (unsigned)N_NODES) &&
                               ((unsigned)d0 < (unsigned)N_NODES) &&
                               mem_bit(bits, s0) && mem_bit(bits, d0);
                    out_mask[i0] = ok0 ? 1.0f : 0.0f;
                }
            }
        }

        if (tid == 0) snext = grabbed;        // publish AFTER work (hides latency)
        __syncthreads();                      // publish visible to block
        c = snext;
        __syncthreads();                      // all reads done before next publish
    }
}

extern "C" void kernel_launch(void* const* d_in, const int* in_sizes, int n_in,
                              void* d_out, int out_size, void* d_ws, size_t ws_size,
                              hipStream_t stream) {
    const float* h  = (const float*)d_in[0];
    const float* W  = (const float*)d_in[1];
    const float* bv = (const float*)d_in[2];
    const int*   ei = (const int*)d_in[3];
    const int E = in_sizes[3] / 2;

    char* ws = (char*)d_ws;
    float*        s32      = (float*)(ws + 0);
    float*        ss       = (float*)(ws + 400000);
    int*          si       = (int*)(ws + 800000);
    int*          hist     = (int*)(ws + 1200000);
    unsigned int* bits     = (unsigned int*)(ws + 1462144);
    int*          queue    = (int*)(ws + 1474944);
    int*          offs     = (int*)(ws + 1562144);
    int*          cursor   = (int*)(ws + 1824288);
    int*          chunkSum = (int*)(ws + 2086432);

    float* out      = (float*)d_out;
    float* out_newh = out;                                  // TOP_K * D_FEAT
    float* out_ids  = out + (size_t)TOP_K * D_FEAT;         // TOP_K
    float* out_mask = out + (size_t)TOP_K * D_FEAT + TOP_K; // E

    hipMemsetAsync(ws + 1200000, 0, 275008, stream);        // hist + bits + queue

    score_kernel<<<N_NODES / 32, 256, 0, stream>>>(h, W, bv, s32, hist);
    scan_chunks_kernel<<<NCHUNK, 256, 0, stream>>>(hist, offs, cursor, chunkSum);
    scatter_kernel<<<(N_NODES + 255) / 256, 256, 0, stream>>>(s32, cursor, offs,
                                                              chunkSum, bits, ss, si);
    bucket_sort_kernel<<<NBINS / 256, 256, 0, stream>>>(offs, chunkSum, bits, ss, si);
    emit_edge_kernel<<<QGRID, 256, 0, stream>>>(h, ss, si, ei, bits, queue,
                                                out_newh, out_ids, out_mask, E);
}

// Round 7
// 235.489 us; speedup vs baseline: 1.4286x; 1.4286x over previous
//
#include <hip/hip_runtime.h>
#include <math.h>

#define N_NODES 100000
#define D_FEAT  256
#define TOP_K   50000
#define NBINS   65536
#define NCHUNK  64          // NBINS / 1024 chunks for the parallel scan
#define CUTPOS  (N_NODES - TOP_K)
#define ROWSTRIDE 260       // 256 + 4 pad: bank = (4g + l + 8i) % 32 -> 2-way = free
#define NBITW   3200        // member bitmask words (ceil(100000/32)=3125, padded)
#define FUSE_GRID   2048    // emit||edge fused kernel (exactly co-resident @8/CU)
#define EMIT_BLOCKS 1408    // split ~ per-partition bytes (both inputs L3-resident,
                            // R5 counter: tail FETCH=38MB of 154MB reads):
                            // emit 153.6MB : edge 64MB ~= 1408 : 640

// clang native vectors: __builtin_nontemporal_store requires these (not the
// HIP_vector_type structs float4/float2).
typedef float  fx4 __attribute__((ext_vector_type(4)));
typedef float  fx2 __attribute__((ext_vector_type(2)));

// Workspace layout (byte offsets, all 16B-aligned):
//         0 : s32      float[N_NODES]   (400,000)
//   400,000 : ss       float[N_NODES]   (400,000)  bucket-sorted scores
//   800,000 : si       int[N_NODES]     (400,000)  bucket-sorted node ids
// 1,200,000 : hist     int[NBINS]       (262,144)  } contiguous zero region
// 1,462,144 : bits     uint[NBITW]      ( 12,800)  } (274,944 B memset)
// 1,562,144 : offs     int[NBINS]       (262,144)  chunk-LOCAL exclusive offsets
// 1,824,288 : cursor   int[NBINS]       (262,144)
// 2,086,432 : chunkSum int[NCHUNK]      (256)

__device__ __forceinline__ int bucket_of(float s) {
    int b = (int)(s * 65536.0f);
    return min(max(b, 0), NBINS - 1);
}

// numpy SIMD float32 exp (FMA universal-intrinsics path) — bit-exact, verified R6.
__device__ __forceinline__ float np_expf(float x) {
    float q  = rintf(x * 1.44269504088896341f);
    float xr = fmaf(-q, 0.693359375f, x);
    xr       = fmaf(-q, -2.12194440e-4f, xr);
    float x2 = xr * xr;
    float p  = 1.9875691500E-4f;
    p = fmaf(p, xr, 1.3981999507E-3f);
    p = fmaf(p, xr, 8.3334519073E-3f);
    p = fmaf(p, xr, 4.1665795894E-2f);
    p = fmaf(p, xr, 1.6666665459E-1f);
    p = fmaf(p, xr, 5.0000001201E-1f);
    p = fmaf(p, x2, xr);
    p = p + 1.0f;
    return ldexpf(p, (int)q);
}

// OpenBLAS sgemv_t emulation, parallelized 8 lanes/node (bit-exact numerics):
// lane 8g+l runs chain l (k = i*8+l, i=0..31, serial fmaf) for node g of its wave;
// merge via shfl_xor 1,2,4 reproduces ((a0+a1)+(a2+a3))+((a4+a5)+(a6+a7)).
// Block = 256 thr = 4 waves = 32 nodes; rows staged to LDS coalesced.
// DO NOT TOUCH the numerics: bit-exact scores gate the top-k tie boundary.
__global__ void score_kernel(const float* __restrict__ h,
                             const float* __restrict__ W,
                             const float* __restrict__ bvec,
                             float* __restrict__ s32,
                             int* __restrict__ hist) {
    __shared__ float rows[32 * ROWSTRIDE];   // 33,280 B
    __shared__ float wl[256];
    int tid  = threadIdx.x;
    int wave = tid >> 6;
    int lane = tid & 63;
    int g    = lane >> 3;    // node within wave's 8
    int l    = lane & 7;     // chain id

    wl[tid] = W[tid];

    // stage this wave's 8 rows: one float4 per lane per row, coalesced 1KB
    int nodeBase = blockIdx.x * 32 + wave * 8;
#pragma unroll
    for (int r = 0; r < 8; ++r) {
        float4 v = ((const float4*)(h + (size_t)(nodeBase + r) * D_FEAT))[lane];
        *((float4*)&rows[(wave * 8 + r) * ROWSTRIDE + lane * 4]) = v;
    }
    __syncthreads();

    // W chain-slice into registers: wreg[i] = W[i*8 + l] (8-way LDS broadcast, free)
    float wreg[32];
#pragma unroll
    for (int i = 0; i < 32; ++i) wreg[i] = wl[i * 8 + l];

    // serial chain: acc = sum_{i} h[node][i*8+l] * W[i*8+l], strict fmaf order
    const float* myrow = &rows[(wave * 8 + g) * ROWSTRIDE];
    float acc = 0.0f;
#pragma unroll
    for (int i = 0; i < 32; ++i)
        acc = fmaf(myrow[i * 8 + l], wreg[i], acc);

    // vhaddps-style adjacent-pairwise merge tree (lane 8g+0 holds node g's z)
    float b01 = acc + __shfl_xor(acc, 1, 64);
    float b23 = b01 + __shfl_xor(b01, 2, 64);
    float z   = b23 + __shfl_xor(b23, 4, 64);

    z = z + bvec[0];
    float t = np_expf(-z);
    float s = 1.0f / (1.0f + t);       // IEEE f32 divide

    if (l == 0) {
        int node = nodeBase + g;
        __builtin_nontemporal_store(s, &s32[node]);   // re-read once, much later
        atomicAdd(&hist[bucket_of(s)], 1);
    }
}

// Parallel chunk scan: 64 blocks x 256 threads, 4 consecutive bins per thread
// (int4 coalesced). Chunk-LOCAL exclusive offsets into offs+cursor, chunk total
// into chunkSum. Global base recomputed in-register by consumer blocks (free).
__global__ void scan_chunks_kernel(const int* __restrict__ hist,
                                   int* __restrict__ offs,
                                   int* __restrict__ cursor,
                                   int* __restrict__ chunkSum) {
    __shared__ int wsum[4];
    int tid  = threadIdx.x;
    int lane = tid & 63;
    int wid  = tid >> 6;
    int base = blockIdx.x * 1024 + tid * 4;

    int4 hv = *((const int4*)(hist + base));
    int e1 = hv.x;
    int e2 = hv.x + hv.y;
    int e3 = e2 + hv.z;
    int tot = e3 + hv.w;

    int incl = tot;
#pragma unroll
    for (int d = 1; d < 64; d <<= 1) {
        int t = __shfl_up(incl, d, 64);
        if (lane >= d) incl += t;
    }
    if (lane == 63) wsum[wid] = incl;
    __syncthreads();
    int wbase = 0;
#pragma unroll
    for (int w = 0; w < 3; ++w)
        if (w < wid) wbase += wsum[w];

    int excl = wbase + (incl - tot);
    int4 ov = make_int4(excl, excl + e1, excl + e2, excl + e3);
    *((int4*)(offs + base))   = ov;
    *((int4*)(cursor + base)) = ov;
    if (tid == 255) chunkSum[blockIdx.x] = excl + tot;
}

// wave-0: exclusive scan of the 64 chunk totals -> sbase (LDS)
__device__ __forceinline__ void build_base(const int* __restrict__ chunkSum,
                                           int* sbase, int tid) {
    if (tid < 64) {
        int v = chunkSum[tid];
        int inc = v;
#pragma unroll
        for (int d = 1; d < 64; d <<= 1) {
            int t = __shfl_up(inc, d, 64);
            if (tid >= d) inc += t;
        }
        sbase[tid] = inc - v;
    }
}

// Scatter + sure-member marking.
//  - Buckets whose global END <= CUTPOS are never read downstream: skip the
//    cursor atomic AND the ss/si writes entirely (~half the scatter work).
//  - Buckets whose global START >= CUTPOS are fully inside the top-k: mark
//    member bit now (removes the emit->edge ordering dependency).
__global__ void scatter_kernel(const float* __restrict__ s32,
                               int* __restrict__ cursor,
                               const int* __restrict__ offs,
                               const int* __restrict__ chunkSum,
                               unsigned int* __restrict__ bits,
                               float* __restrict__ ss,
                               int* __restrict__ si) {
    __shared__ int sbase[64];
    int tid = threadIdx.x;
    build_base(chunkSum, sbase, tid);
    __syncthreads();
    int i = blockIdx.x * 256 + tid;
    if (i >= N_NODES) return;
    float s = s32[i];
    int b = bucket_of(s);
    int bn = b + 1;
    int gend = (bn == NBINS) ? N_NODES : sbase[bn >> 10] + offs[bn];
    if (gend <= CUTPOS) return;               // fully below cut: never read
    int pos = atomicAdd(&cursor[b], 1);       // chunk-local position
    int gbase = sbase[b >> 10];
    ss[gbase + pos] = s;
    si[gbase + pos] = i;
    if (gbase + offs[b] >= CUTPOS)            // fully above cut: sure member
        atomicOr(&bits[(unsigned)i >> 5], 1u << (i & 31));
}

// One thread per bucket; insertion sort ascending by (s asc, idx desc)
// so reversed (descending) order is (s desc, idx asc) — lax.top_k tie rule.
// Buckets entirely below the cut are never read -> skip. The (single)
// boundary bucket marks its suffix's member bits after sorting.
__global__ void bucket_sort_kernel(const int* __restrict__ offs,
                                   const int* __restrict__ chunkSum,
                                   unsigned int* __restrict__ bits,
                                   float* __restrict__ ss,
                                   int* __restrict__ si) {
    __shared__ int sbase[64];
    int tid = threadIdx.x;
    build_base(chunkSum, sbase, tid);
    __syncthreads();
    int b = blockIdx.x * 256 + tid;
    int s0 = sbase[b >> 10] + offs[b];
    int e  = (b == NBINS - 1) ? N_NODES : sbase[(b + 1) >> 10] + offs[b + 1];
    if (e <= CUTPOS) return;
    for (int i = s0 + 1; i < e; ++i) {
        float ks = ss[i];
        int   ki = si[i];
        int j = i - 1;
        while (j >= s0) {
            float ps = ss[j];
            int   pi = si[j];
            bool gt = (ps > ks) || (ps == ks && pi < ki);
            if (!gt) break;
            ss[j + 1] = ps;
            si[j + 1] = pi;
            --j;
        }
        ss[j + 1] = ks;
        si[j + 1] = ki;
    }
    if (s0 < CUTPOS) {                        // boundary bucket: mark suffix
        for (int i = CUTPOS; i < e; ++i) {
            int id = si[i];
            atomicOr(&bits[(unsigned)id >> 5], 1u << (id & 31));
        }
    }
}

__device__ __forceinline__ unsigned mem_bit(const unsigned int* __restrict__ bits,
                                            int s) {
    return (bits[(unsigned)s >> 5] >> (s & 31)) & 1u;
}

// Fused emit||edge (static split — R5's atomic queue serialized per-chunk and
// regressed 100us; independent grid-stride iterations let the HW pipeline).
// Outputs use nontemporal stores: never re-read, and skipping L2/L3 write-
// allocate preserves the L3-resident h/ei working set (R5 counter evidence).
__global__ void emit_edge_kernel(const float* __restrict__ h,
                                 const float* __restrict__ ss,
                                 const int* __restrict__ si,
                                 const int* __restrict__ ei,
                                 const unsigned int* __restrict__ bits,
                                 float* __restrict__ out_newh,
                                 float* __restrict__ out_ids,
                                 float* __restrict__ out_mask,
                                 int E) {
    int tid = threadIdx.x;
    int bid = blockIdx.x;

    if (bid < EMIT_BLOCKS) {
        int lane = tid & 63;
        int wg   = bid * 4 + (tid >> 6);
        for (int row = wg; row < TOP_K; row += EMIT_BLOCKS * 4) {
            int p = N_NODES - 1 - row;
            int id  = si[p];                  // wave-uniform -> broadcast
            float s = ss[p];
            if (lane == 0) __builtin_nontemporal_store((float)id, &out_ids[row]);
            const float4* hv = (const float4*)(h + (size_t)id * D_FEAT);
            float4 v = hv[lane];
            fx4 o = { v.x * s, v.y * s, v.z * s, v.w * s };
            __builtin_nontemporal_store(
                o, (fx4*)(out_newh + (size_t)row * D_FEAT) + lane);
        }
        return;
    }

    // ---- edge partition ----
    __shared__ int sflag;
    if (tid < 64) {                           // int64-vs-int32 storage detect
        int v = ei[2 * tid + 1];
        unsigned long long m = __ballot(v == 0);
        if (tid == 0) sflag = (m == ~0ULL) ? 1 : 0;
    }
    __syncthreads();
    int flag = sflag;

    int npairs = (E + 1) / 2;
    int stride = (FUSE_GRID - EMIT_BLOCKS) * 256;
    for (int k = (bid - EMIT_BLOCKS) * 256 + tid; k < npairs; k += stride) {
        int i0 = 2 * k;
        int i1 = i0 + 1;
        if (i1 < E) {
            int s0, d0, s1, d1;
            if (flag) {                    // int64 storage: value in even dword
                int4 a  = ((const int4*)ei)[k];
                int4 bq = ((const int4*)(ei + 2 * (size_t)E))[k];
                s0 = a.x;  s1 = a.z;
                d0 = bq.x; d1 = bq.z;
            } else {                       // int32 storage
                int2 a  = ((const int2*)ei)[k];
                int2 bq = ((const int2*)(ei + (size_t)E))[k];
                s0 = a.x;  s1 = a.y;
                d0 = bq.x; d1 = bq.y;
            }
            bool ok0 = ((unsigned)s0 < (unsigned)N_NODES) &&
                       ((unsigned)d0 < (unsigned)N_NODES) &&
                       mem_bit(bits, s0) && mem_bit(bits, d0);
            bool ok1 = ((unsigned)s1 < (unsigned)N_NODES) &&
                       ((unsigned)d1 < (unsigned)N_NODES) &&
                       mem_bit(bits, s1) && mem_bit(bits, d1);
            fx2 m = { ok0 ? 1.0f : 0.0f, ok1 ? 1.0f : 0.0f };
            __builtin_nontemporal_store(m, (fx2*)out_mask + k);
        } else {                           // odd-E tail (not hit for E=3.2M)
            int s0, d0;
            if (flag) { s0 = ei[2 * i0]; d0 = ei[2 * ((size_t)E + i0)]; }
            else      { s0 = ei[i0];     d0 = ei[(size_t)E + i0]; }
            bool ok0 = ((unsigned)s0 < (unsigned)N_NODES) &&
                       ((unsigned)d0 < (unsigned)N_NODES) &&
                       mem_bit(bits, s0) && mem_bit(bits, d0);
            __builtin_nontemporal_store(ok0 ? 1.0f : 0.0f, &out_mask[i0]);
        }
    }
}

extern "C" void kernel_launch(void* const* d_in, const int* in_sizes, int n_in,
                              void* d_out, int out_size, void* d_ws, size_t ws_size,
                              hipStream_t stream) {
    const float* h  = (const float*)d_in[0];
    const float* W  = (const float*)d_in[1];
    const float* bv = (const float*)d_in[2];
    const int*   ei = (const int*)d_in[3];
    const int E = in_sizes[3] / 2;

    char* ws = (char*)d_ws;
    float*        s32      = (float*)(ws + 0);
    float*        ss       = (float*)(ws + 400000);
    int*          si       = (int*)(ws + 800000);
    int*          hist     = (int*)(ws + 1200000);
    unsigned int* bits     = (unsigned int*)(ws + 1462144);
    int*          offs     = (int*)(ws + 1562144);
    int*          cursor   = (int*)(ws + 1824288);
    int*          chunkSum = (int*)(ws + 2086432);

    float* out      = (float*)d_out;
    float* out_newh = out;                                  // TOP_K * D_FEAT
    float* out_ids  = out + (size_t)TOP_K * D_FEAT;         // TOP_K
    float* out_mask = out + (size_t)TOP_K * D_FEAT + TOP_K; // E

    (void)hipMemsetAsync(ws + 1200000, 0, 274944, stream);  // hist + bits

    score_kernel<<<N_NODES / 32, 256, 0, stream>>>(h, W, bv, s32, hist);
    scan_chunks_kernel<<<NCHUNK, 256, 0, stream>>>(hist, offs, cursor, chunkSum);
    scatter_kernel<<<(N_NODES + 255) / 256, 256, 0, stream>>>(s32, cursor, offs,
                                                              chunkSum, bits, ss, si);
    bucket_sort_kernel<<<NBINS / 256, 256, 0, stream>>>(offs, chunkSum, bits, ss, si);
    emit_edge_kernel<<<FUSE_GRID, 256, 0, stream>>>(h, ss, si, ei, bits,
                                                    out_newh, out_ids, out_mask, E);
}